// Round 1
// baseline (75.432 us; speedup 1.0000x reference)
//
#include <hip/hip_runtime.h>
#include <hip/hip_bf16.h>

// 4-qubit state: 16 complex amplitudes in registers.
// Index convention (matches reference): wire w is bit (3-w), i.e. wire 0 = MSB (weight 8).

template<int STRIDE>
__device__ __forceinline__ void ry_gate(float re[16], float im[16], float c, float s) {
    #pragma unroll
    for (int base = 0; base < 16; base += 2 * STRIDE) {
        #pragma unroll
        for (int off = 0; off < STRIDE; ++off) {
            const int i0 = base + off, i1 = i0 + STRIDE;
            const float r0 = re[i0], m0 = im[i0], r1 = re[i1], m1 = im[i1];
            re[i0] = c * r0 - s * r1;  im[i0] = c * m0 - s * m1;
            re[i1] = s * r0 + c * r1;  im[i1] = s * m0 + c * m1;
        }
    }
}

template<int STRIDE>
__device__ __forceinline__ void rx_gate(float re[16], float im[16], float c, float s) {
    // [[c, -i s], [-i s, c]]
    #pragma unroll
    for (int base = 0; base < 16; base += 2 * STRIDE) {
        #pragma unroll
        for (int off = 0; off < STRIDE; ++off) {
            const int i0 = base + off, i1 = i0 + STRIDE;
            const float r0 = re[i0], m0 = im[i0], r1 = re[i1], m1 = im[i1];
            re[i0] = c * r0 + s * m1;  im[i0] = c * m0 - s * r1;
            re[i1] = s * m0 + c * r1;  im[i1] = -s * r0 + c * m1;
        }
    }
}

template<int STRIDE>
__device__ __forceinline__ void rz_gate(float re[16], float im[16], float c, float s) {
    // diag(e^{-i t/2}, e^{+i t/2}), c = cos(t/2), s = sin(t/2)
    #pragma unroll
    for (int base = 0; base < 16; base += 2 * STRIDE) {
        #pragma unroll
        for (int off = 0; off < STRIDE; ++off) {
            const int i0 = base + off, i1 = i0 + STRIDE;
            const float r0 = re[i0], m0 = im[i0], r1 = re[i1], m1 = im[i1];
            re[i0] = c * r0 + s * m0;  im[i0] = c * m0 - s * r0;
            re[i1] = c * r1 - s * m1;  im[i1] = s * r1 + c * m1;
        }
    }
}

template<int CMASK, int TMASK>
__device__ __forceinline__ void cnot_gate(float re[16], float im[16]) {
    #pragma unroll
    for (int i = 0; i < 16; ++i) {
        if ((i & CMASK) && !(i & TMASK)) {
            const int j = i | TMASK;
            float t;
            t = re[i]; re[i] = re[j]; re[j] = t;
            t = im[i]; im[i] = im[j]; im[j] = t;
        }
    }
}

__global__ __launch_bounds__(256) void quanv_fused(
    const float* __restrict__ x,      // (B, 784)
    const float* __restrict__ embW,   // (4, 4) row-major
    const float* __restrict__ embB,   // (4,)
    const float* __restrict__ qp,     // (5,)
    const float* __restrict__ linW,   // (10, 784) row-major
    const float* __restrict__ linB,   // (10,)
    float* __restrict__ out)          // (B, 10)
{
    const int b   = blockIdx.x;
    const int tid = threadIdx.x;

    __shared__ float simg[784];
    __shared__ float sred[4][10];

    // Stage image in LDS (coalesced).
    const float* img = x + (size_t)b * 784;
    #pragma unroll
    for (int i = 0; i < 4; ++i) {
        const int idx = tid + 256 * i;
        if (idx < 784) simg[idx] = img[idx];
    }
    __syncthreads();

    float part[10];
    #pragma unroll
    for (int c = 0; c < 10; ++c) part[c] = 0.0f;

    if (tid < 196) {
        const int pi = tid / 14, pj = tid % 14;
        // Patch: [img[2i,2j], img[2i,2j+1], img[2i+1,2j], img[2i+1,2j+1]]
        const float p0 = simg[(2 * pi) * 28 + 2 * pj];
        const float p1 = simg[(2 * pi) * 28 + 2 * pj + 1];
        const float p2 = simg[(2 * pi + 1) * 28 + 2 * pj];
        const float p3 = simg[(2 * pi + 1) * 28 + 2 * pj + 1];

        // Angles: ang[w] = patch . embW[w,:] + embB[w]
        float cA[4], sA[4];
        #pragma unroll
        for (int w = 0; w < 4; ++w) {
            const float a = embB[w] + embW[4 * w + 0] * p0 + embW[4 * w + 1] * p1
                                    + embW[4 * w + 2] * p2 + embW[4 * w + 3] * p3;
            __sincosf(0.5f * a, &sA[w], &cA[w]);
        }

        // Fixed-parameter trig
        float qc[5], qs[5];
        #pragma unroll
        for (int i = 0; i < 5; ++i) __sincosf(0.5f * qp[i], &qs[i], &qc[i]);

        // State after the 4 data RYs: real product state.
        float re[16], im[16];
        #pragma unroll
        for (int idx = 0; idx < 16; ++idx) {
            float v = 1.0f;
            #pragma unroll
            for (int w = 0; w < 4; ++w)
                v *= ((idx >> (3 - w)) & 1) ? sA[w] : cA[w];
            re[idx] = v;
            im[idx] = 0.0f;
        }

        // Fixed circuit tail.
        rx_gate<8>(re, im, qc[0], qs[0]);   // RX(q0, wire0)
        ry_gate<4>(re, im, qc[1], qs[1]);   // RY(q1, wire1)
        rz_gate<2>(re, im, qc[2], qs[2]);   // RZ(q2, wire2)
        cnot_gate<8, 4>(re, im);            // CNOT(0,1)
        rx_gate<1>(re, im, qc[3], qs[3]);   // RX(q3, wire3)
        cnot_gate<2, 1>(re, im);            // CNOT(2,3)
        ry_gate<2>(re, im, qc[4], qs[4]);   // RY(q4, wire2)
        cnot_gate<4, 2>(re, im);            // CNOT(1,2)

        // Z expectations per wire.
        float p[16];
        #pragma unroll
        for (int i = 0; i < 16; ++i) p[i] = re[i] * re[i] + im[i] * im[i];
        float f[4];
        #pragma unroll
        for (int w = 0; w < 4; ++w) {
            const int mask = 8 >> w;
            float acc = 0.0f;
            #pragma unroll
            for (int i = 0; i < 16; ++i) acc += (i & mask) ? -p[i] : p[i];
            f[w] = acc;
        }

        // Partial logits: feats at feature offset tid*4 .. tid*4+3
        #pragma unroll
        for (int c = 0; c < 10; ++c) {
            const float4 wv = *reinterpret_cast<const float4*>(linW + c * 784 + tid * 4);
            part[c] = f[0] * wv.x + f[1] * wv.y + f[2] * wv.z + f[3] * wv.w;
        }
    }

    // Wave (64-lane) shuffle reduction, then cross-wave via LDS.
    #pragma unroll
    for (int c = 0; c < 10; ++c) {
        part[c] += __shfl_down(part[c], 32);
        part[c] += __shfl_down(part[c], 16);
        part[c] += __shfl_down(part[c], 8);
        part[c] += __shfl_down(part[c], 4);
        part[c] += __shfl_down(part[c], 2);
        part[c] += __shfl_down(part[c], 1);
    }
    const int lane = tid & 63;
    const int wv   = tid >> 6;
    if (lane == 0) {
        #pragma unroll
        for (int c = 0; c < 10; ++c) sred[wv][c] = part[c];
    }
    __syncthreads();

    if (tid == 0) {
        float logit[10];
        float m = -1e30f;
        #pragma unroll
        for (int c = 0; c < 10; ++c) {
            logit[c] = sred[0][c] + sred[1][c] + sred[2][c] + sred[3][c] + linB[c];
            m = fmaxf(m, logit[c]);
        }
        float ssum = 0.0f;
        #pragma unroll
        for (int c = 0; c < 10; ++c) ssum += expf(logit[c] - m);
        const float lse = m + logf(ssum);
        #pragma unroll
        for (int c = 0; c < 10; ++c) out[(size_t)b * 10 + c] = logit[c] - lse;
    }
}

extern "C" void kernel_launch(void* const* d_in, const int* in_sizes, int n_in,
                              void* d_out, int out_size, void* d_ws, size_t ws_size,
                              hipStream_t stream) {
    const float* x    = (const float*)d_in[0];
    const float* embW = (const float*)d_in[1];
    const float* embB = (const float*)d_in[2];
    const float* qp   = (const float*)d_in[3];
    const float* linW = (const float*)d_in[4];
    const float* linB = (const float*)d_in[5];
    float* out = (float*)d_out;

    const int B = in_sizes[0] / 784;
    quanv_fused<<<B, 256, 0, stream>>>(x, embW, embB, qp, linW, linB, out);
}